// Round 1
// baseline (1083.975 us; speedup 1.0000x reference)
//
#include <hip/hip_runtime.h>
#include <math.h>

// Problem constants (B,S,D,N,H) = (2,2048,1024,16,64)
#define Bc 2
#define Sc 2048
#define Dc 1024
#define Nc 16
#define Hc 64
#define Mc (Bc*Sc)          // 4096 rows total

typedef float f4 __attribute__((ext_vector_type(4)));

// ---------------------------------------------------------------------------
// Kernel 1: QKV projection.
// q[m][n*64+h] = sum_d x[m][d] * W_Q[n][d][h] + b_Q[n][h]   (same for K,V)
// GEMM per head: (4096 x 1024) x (1024 x 64). Tile 64x64, BK=32.
// grid = (Mc/64, Nc, 3); z selects Q/K/V.
// ---------------------------------------------------------------------------
__global__ __launch_bounds__(256) void qkv_kernel(
    const float* __restrict__ x,
    const float* __restrict__ Wq, const float* __restrict__ Wk, const float* __restrict__ Wv,
    const float* __restrict__ bq, const float* __restrict__ bk, const float* __restrict__ bv,
    float* __restrict__ outq, float* __restrict__ outk, float* __restrict__ outv)
{
    const int which = blockIdx.z;
    const float* W    = which == 0 ? Wq : (which == 1 ? Wk : Wv);
    const float* bias = which == 0 ? bq : (which == 1 ? bk : bv);
    float* out        = which == 0 ? outq : (which == 1 ? outk : outv);

    const int n  = blockIdx.y;        // head
    const int m0 = blockIdx.x * 64;   // row tile base

    __shared__ __align__(16) float As[32][68];  // [k][m], pad 4 -> fp4-aligned rows
    __shared__ __align__(16) float Bs[32][64];  // [k][h]

    const int tid = threadIdx.x;
    const int tx  = tid & 15;
    const int ty  = tid >> 4;

    float acc[4][4] = {};

    for (int kt = 0; kt < Dc / 32; ++kt) {
        __syncthreads();
        // A tile 64x32 from x, store transposed As[k][m]
        #pragma unroll
        for (int t = 0; t < 2; ++t) {
            int f   = tid + t * 256;        // 512 float4 total
            int row = f >> 3;               // 8 float4 per row
            int c4  = f & 7;
            f4 av = *(const f4*)(x + (size_t)(m0 + row) * Dc + kt * 32 + c4 * 4);
            #pragma unroll
            for (int j = 0; j < 4; ++j) As[c4 * 4 + j][row] = av[j];
        }
        // B tile 32x64: contiguous block of W for head n
        const float* Wt = W + (size_t)n * (Dc * Hc) + kt * 32 * Hc;
        #pragma unroll
        for (int t = 0; t < 2; ++t) {
            int f = tid + t * 256;
            *(f4*)(&Bs[0][0] + f * 4) = *(const f4*)(Wt + f * 4);
        }
        __syncthreads();

        #pragma unroll 8
        for (int kk = 0; kk < 32; ++kk) {
            f4 a = *(const f4*)(&As[kk][ty * 4]);
            f4 b = *(const f4*)(&Bs[kk][tx * 4]);
            #pragma unroll
            for (int i = 0; i < 4; ++i)
                #pragma unroll
                for (int j = 0; j < 4; ++j)
                    acc[i][j] = fmaf(a[i], b[j], acc[i][j]);
        }
    }

    f4 bv4 = *(const f4*)(bias + n * Hc + tx * 4);
    #pragma unroll
    for (int i = 0; i < 4; ++i) {
        f4 o;
        #pragma unroll
        for (int j = 0; j < 4; ++j) o[j] = acc[i][j] + bv4[j];
        *(f4*)(out + (size_t)(m0 + ty * 4 + i) * (Nc * Hc) + n * Hc + tx * 4) = o;
    }
}

// ---------------------------------------------------------------------------
// Kernel 2: causal flash attention, fp32.
// One block per (q-tile of 64 rows, head, batch). Online softmax.
// ---------------------------------------------------------------------------
__global__ __launch_bounds__(256) void attn_kernel(
    const float* __restrict__ q, const float* __restrict__ k,
    const float* __restrict__ v, float* __restrict__ z)
{
    const int qt = blockIdx.x;   // 0..31
    const int n  = blockIdx.y;
    const int b  = blockIdx.z;

    __shared__ __align__(16) float Qs[64][68];  // [h][r]
    __shared__ __align__(16) float Ks[64][68];  // [h][c]
    __shared__ __align__(16) float Vs[64][64];  // [c][h]
    __shared__ __align__(16) float Ps[64][68];  // [c][r]

    const int tid = threadIdx.x;
    const int tx  = tid & 15;
    const int ty  = tid >> 4;

    const int mbase = b * Sc + qt * 64;

    // Q tile, transposed store Qs[h][r]
    #pragma unroll
    for (int t = 0; t < 4; ++t) {
        int f   = tid + t * 256;    // 1024 float4
        int row = f >> 4;           // 16 float4 per row
        int c4  = f & 15;
        f4 av = *(const f4*)(q + (size_t)(mbase + row) * (Nc * Hc) + n * Hc + c4 * 4);
        #pragma unroll
        for (int j = 0; j < 4; ++j) Qs[c4 * 4 + j][row] = av[j];
    }

    float acc[4][4] = {};
    float m_prev[4], l_sum[4];
    #pragma unroll
    for (int i = 0; i < 4; ++i) { m_prev[i] = -3.0e38f; l_sum[i] = 0.f; }

    for (int kt = 0; kt <= qt; ++kt) {
        __syncthreads();   // previous iter's Ps/Vs reads done
        // K,V tiles
        #pragma unroll
        for (int t = 0; t < 4; ++t) {
            int f   = tid + t * 256;
            int row = f >> 4;
            int c4  = f & 15;
            size_t src = (size_t)(b * Sc + kt * 64 + row) * (Nc * Hc) + n * Hc + c4 * 4;
            f4 kv = *(const f4*)(k + src);
            #pragma unroll
            for (int j = 0; j < 4; ++j) Ks[c4 * 4 + j][row] = kv[j];
            *(f4*)(&Vs[row][c4 * 4]) = *(const f4*)(v + src);
        }
        __syncthreads();

        // S = Q·K^T  (reduce over h)
        float s[4][4] = {};
        #pragma unroll 8
        for (int h = 0; h < 64; ++h) {
            f4 a  = *(const f4*)(&Qs[h][ty * 4]);
            f4 bb = *(const f4*)(&Ks[h][tx * 4]);
            #pragma unroll
            for (int i = 0; i < 4; ++i)
                #pragma unroll
                for (int j = 0; j < 4; ++j)
                    s[i][j] = fmaf(a[i], bb[j], s[i][j]);
        }

        // mask + online softmax (row stats across the 16 tx-lanes)
        const bool diag = (kt == qt);
        #pragma unroll
        for (int i = 0; i < 4; ++i) {
            const int r = ty * 4 + i;
            float mloc = -3.0e38f;
            #pragma unroll
            for (int j = 0; j < 4; ++j) {
                const int c = tx * 4 + j;
                float sv = s[i][j] * 0.125f;              // 1/sqrt(64)
                if (diag && c > r) sv = -3.0e38f;         // causal mask
                s[i][j] = sv;
                mloc = fmaxf(mloc, sv);
            }
            #pragma unroll
            for (int off = 1; off < 16; off <<= 1)
                mloc = fmaxf(mloc, __shfl_xor(mloc, off, 64));
            const float m_new = fmaxf(m_prev[i], mloc);
            const float alpha = expf(m_prev[i] - m_new);
            float lloc = 0.f;
            #pragma unroll
            for (int j = 0; j < 4; ++j) {
                float p = expf(s[i][j] - m_new);
                s[i][j] = p;
                lloc += p;
            }
            #pragma unroll
            for (int off = 1; off < 16; off <<= 1)
                lloc += __shfl_xor(lloc, off, 64);
            l_sum[i] = l_sum[i] * alpha + lloc;
            m_prev[i] = m_new;
            #pragma unroll
            for (int j = 0; j < 4; ++j) acc[i][j] *= alpha;
        }

        // P transposed into LDS: Ps[c][r]
        #pragma unroll
        for (int i = 0; i < 4; ++i)
            #pragma unroll
            for (int j = 0; j < 4; ++j)
                Ps[tx * 4 + j][ty * 4 + i] = s[i][j];
        __syncthreads();

        // acc += P·V (reduce over c)
        #pragma unroll 8
        for (int c = 0; c < 64; ++c) {
            f4 p  = *(const f4*)(&Ps[c][ty * 4]);
            f4 vv = *(const f4*)(&Vs[c][tx * 4]);
            #pragma unroll
            for (int i = 0; i < 4; ++i)
                #pragma unroll
                for (int j = 0; j < 4; ++j)
                    acc[i][j] = fmaf(p[i], vv[j], acc[i][j]);
        }
    }

    // z[m][n*64+h] = acc / l
    #pragma unroll
    for (int i = 0; i < 4; ++i) {
        const float inv = 1.0f / l_sum[i];
        f4 o;
        #pragma unroll
        for (int j = 0; j < 4; ++j) o[j] = acc[i][j] * inv;
        *(f4*)(z + (size_t)(mbase + ty * 4 + i) * (Nc * Hc) + n * Hc + tx * 4) = o;
    }
}

// ---------------------------------------------------------------------------
// Kernel 3: output projection.
// out[m][d] = sum_{k=n*64+h} z[m][k] * W_O[k][d] + b_O[d]
// W_O (N,H,D) is row-major (1024 x 1024) in k. Tile 64x64, BK=32.
// grid = (Mc/64, Dc/64)
// ---------------------------------------------------------------------------
__global__ __launch_bounds__(256) void oproj_kernel(
    const float* __restrict__ z, const float* __restrict__ Wo,
    const float* __restrict__ bO, float* __restrict__ out)
{
    const int ct = blockIdx.y;        // d col tile
    const int m0 = blockIdx.x * 64;

    __shared__ __align__(16) float As[32][68];
    __shared__ __align__(16) float Bs[32][64];

    const int tid = threadIdx.x;
    const int tx  = tid & 15;
    const int ty  = tid >> 4;

    float acc[4][4] = {};

    for (int kt = 0; kt < (Nc * Hc) / 32; ++kt) {
        __syncthreads();
        #pragma unroll
        for (int t = 0; t < 2; ++t) {
            int f   = tid + t * 256;
            int row = f >> 3;
            int c4  = f & 7;
            f4 av = *(const f4*)(z + (size_t)(m0 + row) * (Nc * Hc) + kt * 32 + c4 * 4);
            #pragma unroll
            for (int j = 0; j < 4; ++j) As[c4 * 4 + j][row] = av[j];
        }
        #pragma unroll
        for (int t = 0; t < 2; ++t) {
            int f   = tid + t * 256;
            int row = f >> 4;               // 16 float4 per 64-col row
            int c4  = f & 15;
            *(f4*)(&Bs[row][c4 * 4]) =
                *(const f4*)(Wo + (size_t)(kt * 32 + row) * Dc + ct * 64 + c4 * 4);
        }
        __syncthreads();

        #pragma unroll 8
        for (int kk = 0; kk < 32; ++kk) {
            f4 a = *(const f4*)(&As[kk][ty * 4]);
            f4 b = *(const f4*)(&Bs[kk][tx * 4]);
            #pragma unroll
            for (int i = 0; i < 4; ++i)
                #pragma unroll
                for (int j = 0; j < 4; ++j)
                    acc[i][j] = fmaf(a[i], b[j], acc[i][j]);
        }
    }

    f4 bv4 = *(const f4*)(bO + ct * 64 + tx * 4);
    #pragma unroll
    for (int i = 0; i < 4; ++i) {
        f4 o;
        #pragma unroll
        for (int j = 0; j < 4; ++j) o[j] = acc[i][j] + bv4[j];
        *(f4*)(out + (size_t)(m0 + ty * 4 + i) * Dc + ct * 64 + tx * 4) = o;
    }
}

// ---------------------------------------------------------------------------
extern "C" void kernel_launch(void* const* d_in, const int* in_sizes, int n_in,
                              void* d_out, int out_size, void* d_ws, size_t ws_size,
                              hipStream_t stream) {
    const float* x  = (const float*)d_in[0];
    const float* Wq = (const float*)d_in[1];
    const float* Wk = (const float*)d_in[2];
    const float* Wv = (const float*)d_in[3];
    const float* Wo = (const float*)d_in[4];
    const float* bq = (const float*)d_in[5];
    const float* bk = (const float*)d_in[6];
    const float* bv = (const float*)d_in[7];
    const float* bO = (const float*)d_in[8];
    float* out = (float*)d_out;

    const size_t perbuf = (size_t)Mc * Nc * Hc;   // 4M floats each
    if (ws_size < 4 * perbuf * sizeof(float)) return;  // need 64MB scratch

    float* qb = (float*)d_ws;
    float* kb = qb + perbuf;
    float* vb = kb + perbuf;
    float* zb = vb + perbuf;

    qkv_kernel<<<dim3(Mc / 64, Nc, 3), 256, 0, stream>>>(
        x, Wq, Wk, Wv, bq, bk, bv, qb, kb, vb);
    attn_kernel<<<dim3(Sc / 64, Nc, Bc), 256, 0, stream>>>(qb, kb, vb, zb);
    oproj_kernel<<<dim3(Mc / 64, Dc / 64, 1), 256, 0, stream>>>(zb, Wo, bO, out);
}

// Round 3
// 255.693 us; speedup vs baseline: 4.2394x; 4.2394x over previous
//
#include <hip/hip_runtime.h>
#include <math.h>

// (B,S,D,N,H) = (2,2048,1024,16,64);  M = B*S = 4096
#define S_ 2048
#define D_ 1024
#define N_ 16
#define H_ 64
#define M_ 4096

typedef float f4 __attribute__((ext_vector_type(4)));
typedef float f16v __attribute__((ext_vector_type(16)));
typedef short s8v __attribute__((ext_vector_type(8)));   // 8 bf16
typedef short s4v __attribute__((ext_vector_type(4)));   // 4 bf16 (8B - for LDS on 136B rows)
typedef unsigned short u16;

#define MFMA32(a, b, c) __builtin_amdgcn_mfma_f32_32x32x16_bf16((a), (b), (c), 0, 0, 0)

__device__ __forceinline__ u16 f2bf(float x) {
    unsigned int u = __float_as_uint(x);
    u += 0x7fffu + ((u >> 16) & 1u);
    return (u16)(u >> 16);
}
union FragU { unsigned int u[4]; s4v h[2]; s8v v; };

// LDS access on 8B-aligned (not 16B) addresses: explicit b64 pairs.
__device__ __forceinline__ s8v ld8(const u16* p) {
    FragU f;
    f.h[0] = *(const s4v*)(p);
    f.h[1] = *(const s4v*)(p + 4);
    return f.v;
}
__device__ __forceinline__ void st8(u16* p, s8v x) {
    FragU f; f.v = x;
    *(s4v*)(p)     = f.h[0];
    *(s4v*)(p + 4) = f.h[1];
}

// ===========================================================================
// Prep 1: x fp32 -> bf16
// ===========================================================================
__global__ __launch_bounds__(256) void cvt_x(const float* __restrict__ x,
                                             u16* __restrict__ xb)
{
    int i = (blockIdx.x * 256 + threadIdx.x) * 8;
    f4 a = *(const f4*)(x + i);
    f4 b = *(const f4*)(x + i + 4);
    unsigned long long p0 =
        (unsigned long long)f2bf(a[0]) | ((unsigned long long)f2bf(a[1]) << 16) |
        ((unsigned long long)f2bf(a[2]) << 32) | ((unsigned long long)f2bf(a[3]) << 48);
    unsigned long long p1 =
        (unsigned long long)f2bf(b[0]) | ((unsigned long long)f2bf(b[1]) << 16) |
        ((unsigned long long)f2bf(b[2]) << 32) | ((unsigned long long)f2bf(b[3]) << 48);
    *(unsigned long long*)(xb + i)     = p0;
    *(unsigned long long*)(xb + i + 4) = p1;
}

// ===========================================================================
// Prep 2: W_{Q,K,V} [16][1024][64] -> Wc[c][d] bf16, c = which*1024 + n*64 + h
// ===========================================================================
__global__ __launch_bounds__(256) void transW_kernel(
    const float* __restrict__ Wq, const float* __restrict__ Wk, const float* __restrict__ Wv,
    u16* __restrict__ Wc)
{
    const int which = blockIdx.z, n = blockIdx.y, dt = blockIdx.x;
    const float* W = which == 0 ? Wq : (which == 1 ? Wk : Wv);
    __shared__ float t[64][65];   // t[h][d]
    const int tid = threadIdx.x;
    #pragma unroll
    for (int it = 0; it < 4; ++it) {
        int c = tid + it * 256;            // 1024 f4 chunks
        int d = c >> 4, h4 = c & 15;
        f4 v = *(const f4*)(W + ((size_t)n * 1024 + dt * 64 + d) * 64 + h4 * 4);
        #pragma unroll
        for (int j = 0; j < 4; ++j) t[h4 * 4 + j][d] = v[j];
    }
    __syncthreads();
    #pragma unroll
    for (int it = 0; it < 4; ++it) {
        int c = tid + it * 256;
        int h = c >> 4, d4 = c & 15;
        size_t o = (size_t)(which * 1024 + n * 64 + h) * 1024 + dt * 64 + d4 * 4;
        *(unsigned long long*)(Wc + o) =
            (unsigned long long)f2bf(t[h][d4 * 4 + 0]) |
            ((unsigned long long)f2bf(t[h][d4 * 4 + 1]) << 16) |
            ((unsigned long long)f2bf(t[h][d4 * 4 + 2]) << 32) |
            ((unsigned long long)f2bf(t[h][d4 * 4 + 3]) << 48);
    }
}

// ===========================================================================
// Prep 3: W_O [1024 nh][1024 d] -> WoT[d][nh] bf16
// ===========================================================================
__global__ __launch_bounds__(256) void transWo_kernel(
    const float* __restrict__ Wo, u16* __restrict__ WoT)
{
    const int rt = blockIdx.y, ct = blockIdx.x;   // rt: nh-tile, ct: d-tile
    __shared__ float t[64][65];                   // t[d][nh]
    const int tid = threadIdx.x;
    #pragma unroll
    for (int it = 0; it < 4; ++it) {
        int c = tid + it * 256;
        int r = c >> 4, c4 = c & 15;
        f4 v = *(const f4*)(Wo + (size_t)(rt * 64 + r) * 1024 + ct * 64 + c4 * 4);
        #pragma unroll
        for (int j = 0; j < 4; ++j) t[c4 * 4 + j][r] = v[j];
    }
    __syncthreads();
    #pragma unroll
    for (int it = 0; it < 4; ++it) {
        int c = tid + it * 256;
        int d = c >> 4, r4 = c & 15;
        size_t o = (size_t)(ct * 64 + d) * 1024 + rt * 64 + r4 * 4;
        *(unsigned long long*)(WoT + o) =
            (unsigned long long)f2bf(t[d][r4 * 4 + 0]) |
            ((unsigned long long)f2bf(t[d][r4 * 4 + 1]) << 16) |
            ((unsigned long long)f2bf(t[d][r4 * 4 + 2]) << 32) |
            ((unsigned long long)f2bf(t[d][r4 * 4 + 3]) << 48);
    }
}

// Prep 4: bias concat (fp32)
__global__ void bcat_kernel(const float* bq, const float* bk, const float* bv, float* bc)
{
    int i = blockIdx.x * 256 + threadIdx.x;   // 3072
    bc[i] = i < 1024 ? bq[i] : (i < 2048 ? bk[i - 1024] : bv[i - 2048]);
}

// ===========================================================================
// bf16 GEMM: C[m][c] = sum_k A[m][k]*B[c][k] + bias[c]
// A [4096][1024], B [NC][1024] bf16 (B pre-transposed). 128x128 tile, BK=64,
// 4 waves (2x2), wave tile 64x64 via 2x2 32x32x16 MFMAs.
// LDS rows padded to 68 u16 (136B): bank rotation 2/row -> conflict-free
// fragment reads; 8B alignment only, so all LDS traffic is b64 pairs.
// MODE 0: qkv epilogue (bf16; cols<1024 q, <2048 k, else v transposed),
//         LDS-bounced for coalesced 16B stores.
// MODE 1: fp32 out + bias, direct stores.
// ===========================================================================
template<int MODE>
__global__ __launch_bounds__(256) void gemm_bf16(
    const u16* __restrict__ A, const u16* __restrict__ B,
    const float* __restrict__ bias,
    u16* __restrict__ outq, u16* __restrict__ outk, u16* __restrict__ outvT,
    float* __restrict__ outf)
{
    __shared__ u16 sm[17408];           // 2 * 128*68
    u16* Ash = sm;
    u16* Bsh = sm + 8704;

    const int tid = threadIdx.x;
    const int lane = tid & 63, w = tid >> 6;
    const int wm = w & 1, wn = w >> 1;
    const int l31 = lane & 31, hi = lane >> 5;
    const int m0 = blockIdx.x * 128, n0 = blockIdx.y * 128;

    f16v acc[2][2];
    #pragma unroll
    for (int a = 0; a < 2; ++a)
        #pragma unroll
        for (int b = 0; b < 2; ++b)
            #pragma unroll
            for (int r = 0; r < 16; ++r) acc[a][b][r] = 0.f;

    for (int kt = 0; kt < 16; ++kt) {
        __syncthreads();
        #pragma unroll
        for (int t = 0; t < 4; ++t) {
            int c = tid + t * 256;          // 1024 chunks of 8 u16 per array
            int row = c >> 3, c8 = c & 7;
            int idx = row * 68 + c8 * 8;
            s8v av = *(const s8v*)(A + (size_t)(m0 + row) * 1024 + kt * 64 + c8 * 8);
            s8v bv = *(const s8v*)(B + (size_t)(n0 + row) * 1024 + kt * 64 + c8 * 8);
            st8(&Ash[idx], av);
            st8(&Bsh[idx], bv);
        }
        __syncthreads();
        #pragma unroll
        for (int ks = 0; ks < 4; ++ks) {
            const int off = (2 * ks + hi) * 8;
            s8v af[2], bf[2];
            #pragma unroll
            for (int mb = 0; mb < 2; ++mb)
                af[mb] = ld8(&Ash[(64 * wm + 32 * mb + l31) * 68 + off]);
            #pragma unroll
            for (int nb = 0; nb < 2; ++nb)
                bf[nb] = ld8(&Bsh[(64 * wn + 32 * nb + l31) * 68 + off]);
            #pragma unroll
            for (int mb = 0; mb < 2; ++mb)
                #pragma unroll
                for (int nb = 0; nb < 2; ++nb)
                    acc[mb][nb] = MFMA32(af[mb], bf[nb], acc[mb][nb]);
        }
    }

    __syncthreads();   // staging buffers dead; reuse for epilogue bounce

    if constexpr (MODE == 0) {
        u16* Zw = sm + w * 4096;            // per-wave 64x64 bf16 tile (8KB)
        const int which = n0 >> 10;         // 0=q, 1=k, 2=v
        #pragma unroll
        for (int nb = 0; nb < 2; ++nb) {
            int nhl = 32 * nb + l31;
            float bv = bias[n0 + 64 * wn + nhl];
            #pragma unroll
            for (int mb = 0; mb < 2; ++mb)
                #pragma unroll
                for (int r = 0; r < 16; ++r) {
                    int ml = 32 * mb + (r & 3) + 8 * (r >> 2) + 4 * hi;
                    u16 hv = f2bf(acc[mb][nb][r] + bv);
                    int idx = (which == 2)
                        ? nhl * 64 + (ml ^ ((nhl & 7) << 3))    // vT: [nh][m]
                        : ml * 64 + (nhl ^ ((ml & 7) << 3));    // q/k: [m][nh]
                    Zw[idx] = hv;
                }
        }
        __syncthreads();
        const int gmb = m0 + 64 * wm;
        const int gnb = n0 + 64 * wn;
        #pragma unroll
        for (int it = 0; it < 8; ++it) {
            int c = lane + it * 64;         // 512 chunks per wave
            int row = c >> 3, c8 = c & 7;
            int idx = row * 64 + 8 * (c8 ^ (row & 7));
            s8v val = *(const s8v*)&Zw[idx];    // 16B aligned (LD=64)
            if (which == 0)
                *(s8v*)(outq + (size_t)(gmb + row) * 1024 + gnb + c8 * 8) = val;
            else if (which == 1)
                *(s8v*)(outk + (size_t)(gmb + row) * 1024 + (gnb - 1024) + c8 * 8) = val;
            else
                *(s8v*)(outvT + (size_t)(gnb - 2048 + row) * 4096 + gmb + c8 * 8) = val;
        }
    } else {
        #pragma unroll
        for (int nb = 0; nb < 2; ++nb) {
            int gcol = n0 + 64 * wn + 32 * nb + l31;
            float bv = bias[gcol];
            #pragma unroll
            for (int mb = 0; mb < 2; ++mb)
                #pragma unroll
                for (int r = 0; r < 16; ++r) {
                    int gm = m0 + 64 * wm + 32 * mb + (r & 3) + 8 * (r >> 2) + 4 * hi;
                    outf[(size_t)gm * 1024 + gcol] = acc[mb][nb][r] + bv;
                }
        }
    }
}

// ===========================================================================
// Flash attention, bf16 MFMA. Block = 128 q rows x head x batch, 4 waves
// (32 q rows each). Swapped QK^T (lane owns one q col), online softmax in
// registers, in-register P fragization via one shfl_xor(32) exchange.
// ===========================================================================
#define SCALE_LOG2 (0.125f * 1.44269504088896340736f)

__global__ __launch_bounds__(256) void attn_mfma(
    const u16* __restrict__ qp, const u16* __restrict__ kp,
    const u16* __restrict__ vTp, u16* __restrict__ zp)
{
    __shared__ u16 sm[8704];            // Ksh[64*68] + Vsh[64*68]
    u16* Ksh = sm;
    u16* Vsh = sm + 4352;

    const int tid = threadIdx.x;
    const int lane = tid & 63, w = tid >> 6;
    const int l31 = lane & 31, hi = lane >> 5;
    const int qt = (int)gridDim.x - 1 - (int)blockIdx.x;   // heavy tiles first
    const int n = blockIdx.y, b = blockIdx.z;
    const int q0 = qt * 128;
    const int qrow = q0 + 32 * w + l31;
    const size_t mrow = (size_t)b * 2048 + qrow;

    // Q fragments (B-operand), hoisted: lane holds Q[q=l31][h=16c+8hi+j]
    s8v qf[4];
    #pragma unroll
    for (int c = 0; c < 4; ++c)
        qf[c] = *(const s8v*)(qp + mrow * 1024 + n * 64 + c * 16 + hi * 8);

    f16v acc[2];
    #pragma unroll
    for (int mb = 0; mb < 2; ++mb)
        #pragma unroll
        for (int r = 0; r < 16; ++r) acc[mb][r] = 0.f;
    float mrun = -1e30f, lrun = 0.f;
    const int nkt = 2 * qt + 2;
    const int wqmax = q0 + 32 * w + 31;

    for (int kt = 0; kt < nkt; ++kt) {
        __syncthreads();
        // stage K [s][h] and V^T [h][s], rows padded to 68
        #pragma unroll
        for (int t2 = 0; t2 < 2; ++t2) {
            int c = tid + t2 * 256;         // 512 chunks per array
            int row = c >> 3, c8 = c & 7;
            int idx = row * 68 + c8 * 8;
            s8v kv = *(const s8v*)(kp + ((size_t)b * 2048 + kt * 64 + row) * 1024 + n * 64 + c8 * 8);
            s8v vv = *(const s8v*)(vTp + ((size_t)n * 64 + row) * 4096 + b * 2048 + kt * 64 + c8 * 8);
            st8(&Ksh[idx], kv);
            st8(&Vsh[idx], vv);
        }
        __syncthreads();
        if (64 * kt > wqmax) continue;      // fully masked for this wave

        // ---- QK^T (swapped): sf[t] = S[s=32t+..][q=l31] ----
        f16v sf[2];
        #pragma unroll
        for (int t = 0; t < 2; ++t) {
            #pragma unroll
            for (int r = 0; r < 16; ++r) sf[t][r] = 0.f;
            int row = 32 * t + l31;
            #pragma unroll
            for (int c = 0; c < 4; ++c) {
                s8v kf = ld8(&Ksh[row * 68 + (2 * c + hi) * 8]);
                sf[t] = MFMA32(kf, qf[c], sf[t]);
            }
        }

        // ---- online softmax (lane owns one q; hi-halves exchanged) ----
        float mloc = -1e30f;
        #pragma unroll
        for (int t = 0; t < 2; ++t)
            #pragma unroll
            for (int r = 0; r < 16; ++r) {
                float sc = sf[t][r] * SCALE_LOG2;
                int sg = kt * 64 + 32 * t + (r & 3) + 8 * (r >> 2) + 4 * hi;
                if (sg > qrow) sc = -1e30f;
                sf[t][r] = sc;
                mloc = fmaxf(mloc, sc);
            }
        mloc = fmaxf(mloc, __shfl_xor(mloc, 32, 64));
        float mnew = fmaxf(mrun, mloc);
        float alpha = exp2f(mrun - mnew);
        float ls = 0.f;
        #pragma unroll
        for (int t = 0; t < 2; ++t)
            #pragma unroll
            for (int r = 0; r < 16; ++r) {
                float pv = exp2f(sf[t][r] - mnew);
                sf[t][r] = pv;
                ls += pv;
            }
        ls += __shfl_xor(ls, 32, 64);
        lrun = lrun * alpha + ls;
        mrun = mnew;
        #pragma unroll
        for (int mb = 0; mb < 2; ++mb)
            #pragma unroll
            for (int r = 0; r < 16; ++r) acc[mb][r] *= alpha;

        // ---- P fragization (B-operand [k=s][col=q]) ----
        // lane holds P[s=32t+(r&3)+8(r>>2)+4hi][q=l31]; target elem j of
        // frag c: s = 16c+8hi+j. jj0-3 from hi_src=0, jj4-7 from hi_src=1,
        // both at source idx = 2c + hi_target.
        s8v pf[4];
        #pragma unroll
        for (int c = 0; c < 4; ++c) {
            const int i0 = 2 * c, i1 = 2 * c + 1;
            const int t0 = i0 >> 2, u0 = i0 & 3;
            const int t1 = i1 >> 2, u1 = i1 & 3;
            unsigned int f00 = (unsigned int)f2bf(sf[t0][4 * u0 + 0]) |
                               ((unsigned int)f2bf(sf[t0][4 * u0 + 1]) << 16);
            unsigned int f01 = (unsigned int)f2bf(sf[t0][4 * u0 + 2]) |
                               ((unsigned int)f2bf(sf[t0][4 * u0 + 3]) << 16);
            unsigned int f10 = (unsigned int)f2bf(sf[t1][4 * u1 + 0]) |
                               ((unsigned int)f2bf(sf[t1][4 * u1 + 1]) << 16);
            unsigned int f11 = (unsigned int)f2bf(sf[t1][4 * u1 + 2]) |
                               ((unsigned int)f2bf(sf[t1][4 * u1 + 3]) << 16);
            unsigned int s0 = hi ? f00 : f10, s1 = hi ? f01 : f11;
            unsigned int r0 = __shfl_xor(s0, 32, 64);
            unsigned int r1 = __shfl_xor(s1, 32, 64);
            FragU f;
            f.u[0] = hi ? r0 : f00;  f.u[1] = hi ? r1 : f01;
            f.u[2] = hi ? f10 : r0;  f.u[3] = hi ? f11 : r1;
            pf[c] = f.v;
        }

        // ---- PV: acc[mb] += V^T x P  (D[h][q]) ----
        #pragma unroll
        for (int mb = 0; mb < 2; ++mb) {
            int row = 32 * mb + l31;
            #pragma unroll
            for (int c = 0; c < 4; ++c) {
                s8v vf = ld8(&Vsh[row * 68 + (2 * c + hi) * 8]);
                acc[mb] = MFMA32(vf, pf[c], acc[mb]);
            }
        }
    }

    // ---- epilogue: z = acc/l -> bf16, per-wave LDS bounce (4KB regions,
    //      w*2048 in [0,8192) -- collision of round 2 fixed), 16B stores ----
    __syncthreads();
    float linv = 1.0f / lrun;
    u16* Z = sm + w * 2048;                 // 32 rows x 64 h
    #pragma unroll
    for (int mb = 0; mb < 2; ++mb)
        #pragma unroll
        for (int r = 0; r < 16; ++r) {
            int hcol = 32 * mb + (r & 3) + 8 * (r >> 2) + 4 * hi;
            int idx = l31 * 64 + (hcol ^ ((l31 & 7) << 3));
            Z[idx] = f2bf(acc[mb][r] * linv);
        }
    __syncthreads();
    #pragma unroll
    for (int it = 0; it < 4; ++it) {
        int c = lane + it * 64;             // 256 chunks per wave
        int row = c >> 3, c8 = c & 7;
        int idx = row * 64 + 8 * (c8 ^ (row & 7));
        *(s8v*)(zp + ((size_t)b * 2048 + q0 + 32 * w + row) * 1024 + n * 64 + c8 * 8) =
            *(const s8v*)&Z[idx];
    }
}

// ===========================================================================
extern "C" void kernel_launch(void* const* d_in, const int* in_sizes, int n_in,
                              void* d_out, int out_size, void* d_ws, size_t ws_size,
                              hipStream_t stream) {
    const float* x  = (const float*)d_in[0];
    const float* Wq = (const float*)d_in[1];
    const float* Wk = (const float*)d_in[2];
    const float* Wv = (const float*)d_in[3];
    const float* Wo = (const float*)d_in[4];
    const float* bq = (const float*)d_in[5];
    const float* bk = (const float*)d_in[6];
    const float* bv = (const float*)d_in[7];
    const float* bO = (const float*)d_in[8];
    float* out = (float*)d_out;

    char* p = (char*)d_ws;
    size_t o = 0;
    auto alloc = [&](size_t bytes) { char* r = p + o; o += bytes; return r; };
    const size_t MB8 = (size_t)M_ * D_ * 2;            // 8 MB bf16 buffer
    u16* xb   = (u16*)alloc(MB8);
    u16* Wc   = (u16*)alloc((size_t)3072 * 1024 * 2);
    u16* WoT  = (u16*)alloc((size_t)1024 * 1024 * 2);
    float* bc = (float*)alloc(65536);
    u16* qb   = (u16*)alloc(MB8);
    u16* kb   = (u16*)alloc(MB8);
    u16* vTb  = (u16*)alloc(MB8);
    if (ws_size < o) return;
    u16* zb = xb;   // x dead after qkv gemm; reuse for z

    cvt_x<<<2048, 256, 0, stream>>>(x, xb);
    transW_kernel<<<dim3(16, 16, 3), 256, 0, stream>>>(Wq, Wk, Wv, Wc);
    transWo_kernel<<<dim3(16, 16), 256, 0, stream>>>(Wo, WoT);
    bcat_kernel<<<12, 256, 0, stream>>>(bq, bk, bv, bc);
    gemm_bf16<0><<<dim3(32, 24), 256, 0, stream>>>(
        xb, Wc, bc, qb, kb, vTb, nullptr);
    attn_mfma<<<dim3(16, 16, 2), 256, 0, stream>>>(qb, kb, vTb, zb);
    gemm_bf16<1><<<dim3(32, 8), 256, 0, stream>>>(
        zb, WoT, bO, nullptr, nullptr, nullptr, out);
}

// Round 4
// 231.203 us; speedup vs baseline: 4.6884x; 1.1059x over previous
//
#include <hip/hip_runtime.h>
#include <math.h>

// (B,S,D,N,H) = (2,2048,1024,16,64);  M = B*S = 4096
#define S_ 2048
#define D_ 1024
#define M_ 4096

typedef float f4 __attribute__((ext_vector_type(4)));
typedef float f16v __attribute__((ext_vector_type(16)));
typedef short s8v __attribute__((ext_vector_type(8)));   // 8 bf16 = 16B
typedef unsigned short u16;

#define MFMA32(a,b,c) __builtin_amdgcn_mfma_f32_32x32x16_bf16((a),(b),(c),0,0,0)
#define QSCALE 0.1803368801111204f      // 0.125 * log2(e): scores land in log2 units
#define NINF  -1e30f

__device__ __forceinline__ u16 f2bf(float x) {
    unsigned int u = __float_as_uint(x);
    u += 0x7fffu + ((u >> 16) & 1u);
    return (u16)(u >> 16);
}
__device__ __forceinline__ unsigned int cvtpk(float lo, float hi) {
    unsigned int r;
    asm("v_cvt_pk_bf16_f32 %0, %1, %2" : "=v"(r) : "v"(lo), "v"(hi));
    return r;
}
// async global->LDS, 16B per lane. LDS dest = wave-uniform base + lane*16.
__device__ __forceinline__ void gload16(const void* g, void* l) {
    __builtin_amdgcn_global_load_lds(
        (const __attribute__((address_space(1))) unsigned int*)g,
        (__attribute__((address_space(3))) unsigned int*)l, 16, 0, 0);
}
union FragU { unsigned int u[4]; s8v v; };

// ===========================================================================
// Prep 1: x fp32 -> bf16
// ===========================================================================
__global__ __launch_bounds__(256) void cvt_x(const float* __restrict__ x,
                                             u16* __restrict__ xb)
{
    int i = (blockIdx.x * 256 + threadIdx.x) * 8;
    f4 a = *(const f4*)(x + i);
    f4 b = *(const f4*)(x + i + 4);
    unsigned long long p0 =
        (unsigned long long)f2bf(a[0]) | ((unsigned long long)f2bf(a[1]) << 16) |
        ((unsigned long long)f2bf(a[2]) << 32) | ((unsigned long long)f2bf(a[3]) << 48);
    unsigned long long p1 =
        (unsigned long long)f2bf(b[0]) | ((unsigned long long)f2bf(b[1]) << 16) |
        ((unsigned long long)f2bf(b[2]) << 32) | ((unsigned long long)f2bf(b[3]) << 48);
    *(unsigned long long*)(xb + i)     = p0;
    *(unsigned long long*)(xb + i + 4) = p1;
}

// ===========================================================================
// Prep 2: W_{Q,K,V} [16][1024][64] -> Wc[c][d] bf16, c = which*1024 + n*64 + h
// ===========================================================================
__global__ __launch_bounds__(256) void transW_kernel(
    const float* __restrict__ Wq, const float* __restrict__ Wk, const float* __restrict__ Wv,
    u16* __restrict__ Wc)
{
    const int which = blockIdx.z, n = blockIdx.y, dt = blockIdx.x;
    const float* W = which == 0 ? Wq : (which == 1 ? Wk : Wv);
    __shared__ float t[64][65];   // t[h][d]
    const int tid = threadIdx.x;
    #pragma unroll
    for (int it = 0; it < 4; ++it) {
        int c = tid + it * 256;
        int d = c >> 4, h4 = c & 15;
        f4 v = *(const f4*)(W + ((size_t)n * 1024 + dt * 64 + d) * 64 + h4 * 4);
        #pragma unroll
        for (int j = 0; j < 4; ++j) t[h4 * 4 + j][d] = v[j];
    }
    __syncthreads();
    #pragma unroll
    for (int it = 0; it < 4; ++it) {
        int c = tid + it * 256;
        int h = c >> 4, d4 = c & 15;
        size_t o = (size_t)(which * 1024 + n * 64 + h) * 1024 + dt * 64 + d4 * 4;
        *(unsigned long long*)(Wc + o) =
            (unsigned long long)f2bf(t[h][d4 * 4 + 0]) |
            ((unsigned long long)f2bf(t[h][d4 * 4 + 1]) << 16) |
            ((unsigned long long)f2bf(t[h][d4 * 4 + 2]) << 32) |
            ((unsigned long long)f2bf(t[h][d4 * 4 + 3]) << 48);
    }
}

// ===========================================================================
// Prep 3: W_O [1024 nh][1024 d] -> WoT[d][nh] bf16
// ===========================================================================
__global__ __launch_bounds__(256) void transWo_kernel(
    const float* __restrict__ Wo, u16* __restrict__ WoT)
{
    const int rt = blockIdx.y, ct = blockIdx.x;
    __shared__ float t[64][65];                   // t[d][nh]
    const int tid = threadIdx.x;
    #pragma unroll
    for (int it = 0; it < 4; ++it) {
        int c = tid + it * 256;
        int r = c >> 4, c4 = c & 15;
        f4 v = *(const f4*)(Wo + (size_t)(rt * 64 + r) * 1024 + ct * 64 + c4 * 4);
        #pragma unroll
        for (int j = 0; j < 4; ++j) t[c4 * 4 + j][r] = v[j];
    }
    __syncthreads();
    #pragma unroll
    for (int it = 0; it < 4; ++it) {
        int c = tid + it * 256;
        int d = c >> 4, r4 = c & 15;
        size_t o = (size_t)(ct * 64 + d) * 1024 + rt * 64 + r4 * 4;
        *(unsigned long long*)(WoT + o) =
            (unsigned long long)f2bf(t[d][r4 * 4 + 0]) |
            ((unsigned long long)f2bf(t[d][r4 * 4 + 1]) << 16) |
            ((unsigned long long)f2bf(t[d][r4 * 4 + 2]) << 32) |
            ((unsigned long long)f2bf(t[d][r4 * 4 + 3]) << 48);
    }
}

// Prep 4: bias concat (fp32)
__global__ void bcat_kernel(const float* bq, const float* bk, const float* bv, float* bc)
{
    int i = blockIdx.x * 256 + threadIdx.x;   // 3072
    bc[i] = i < 1024 ? bq[i] : (i < 2048 ? bk[i - 1024] : bv[i - 2048]);
}

// ===========================================================================
// bf16 GEMM (m97 structure): C[m][c] = sum_k A[m][k]*B[c][k] + bias[c]
// 128x128 tile, BK=64, single-buffer LDS, global_load_lds width-16 staging.
// LDS tile [128 rows][8 chunks of 16B], both-sides XOR swizzle:
//   LDS[row][c] = G[row][c ^ (row&7)]  (pre-swizzled global source),
//   read chunk g at LDS[row][g ^ (row&7)] -> conflict-free ds_read_b128.
// MODE 0: qkv epilogue (bf16; q gets QSCALE; v stored transposed), LDS-bounced.
// MODE 1: fp32 out + bias.
// ===========================================================================
template<int MODE>
__global__ __launch_bounds__(256) void gemm_bf16(
    const u16* __restrict__ A, const u16* __restrict__ B,
    const float* __restrict__ bias,
    u16* __restrict__ outq, u16* __restrict__ outk, u16* __restrict__ outvT,
    float* __restrict__ outf)
{
    __shared__ u16 sm[16384];           // Ash[128*64] + Bsh[128*64] = 32KB
    u16* Ash = sm;
    u16* Bsh = sm + 8192;

    const int tid = threadIdx.x;
    const int lane = tid & 63, w = tid >> 6;
    const int wm = w & 1, wn = w >> 1;
    const int l31 = lane & 31, hi = lane >> 5;
    const int m0 = blockIdx.x * 128, n0 = blockIdx.y * 128;
    const int srow = lane >> 3;                 // staging row-in-block 0..7
    const int sc8 = (lane & 7) ^ srow;          // pre-swizzled source chunk
    const int rx = l31 & 7;                     // read-side swizzle key

    f16v acc[2][2];
    #pragma unroll
    for (int a = 0; a < 2; ++a)
        #pragma unroll
        for (int b = 0; b < 2; ++b)
            #pragma unroll
            for (int r = 0; r < 16; ++r) acc[a][b][r] = 0.f;

    for (int kt = 0; kt < 16; ++kt) {
        __syncthreads();                        // prev reads done
        #pragma unroll
        for (int i = 0; i < 4; ++i) {           // 4 waves x 4 issues x 1KB per array
            const int rb = (i * 4 + w) * 8;
            const int row = rb + srow;
            gload16(A + (size_t)(m0 + row) * 1024 + kt * 64 + sc8 * 8, Ash + rb * 64);
            gload16(B + (size_t)(n0 + row) * 1024 + kt * 64 + sc8 * 8, Bsh + rb * 64);
        }
        __syncthreads();                        // implicit vmcnt(0) drain -> ready
        #pragma unroll
        for (int ks = 0; ks < 4; ++ks) {
            s8v af[2], bf[2];
            #pragma unroll
            for (int mb = 0; mb < 2; ++mb)
                af[mb] = *(const s8v*)&Ash[(64 * wm + 32 * mb + l31) * 64 +
                                           ((2 * ks + hi) ^ rx) * 8];
            #pragma unroll
            for (int nb = 0; nb < 2; ++nb)
                bf[nb] = *(const s8v*)&Bsh[(64 * wn + 32 * nb + l31) * 64 +
                                           ((2 * ks + hi) ^ rx) * 8];
            #pragma unroll
            for (int mb = 0; mb < 2; ++mb)
                #pragma unroll
                for (int nb = 0; nb < 2; ++nb)
                    acc[mb][nb] = MFMA32(af[mb], bf[nb], acc[mb][nb]);
        }
    }

    __syncthreads();   // staging dead; reuse LDS for epilogue bounce

    if constexpr (MODE == 0) {
        u16* Zw = sm + w * 4096;            // per-wave 64x64 bf16 tile (8KB)
        const int which = n0 >> 10;         // 0=q, 1=k, 2=v
        #pragma unroll
        for (int nb = 0; nb < 2; ++nb) {
            int nhl = 32 * nb + l31;
            float bv = bias[n0 + 64 * wn + nhl];
            #pragma unroll
            for (int mb = 0; mb < 2; ++mb)
                #pragma unroll
                for (int r = 0; r < 16; ++r) {
                    int ml = 32 * mb + (r & 3) + 8 * (r >> 2) + 4 * hi;
                    float vv = acc[mb][nb][r] + bv;
                    if (which == 0) vv *= QSCALE;   // fold softmax scale into q
                    u16 hv = f2bf(vv);
                    int idx = (which == 2)
                        ? nhl * 64 + (ml ^ ((nhl & 7) << 3))    // vT: [nh][m]
                        : ml * 64 + (nhl ^ ((ml & 7) << 3));    // q/k: [m][nh]
                    Zw[idx] = hv;
                }
        }
        __syncthreads();
        const int gmb = m0 + 64 * wm;
        const int gnb = n0 + 64 * wn;
        #pragma unroll
        for (int it = 0; it < 8; ++it) {
            int c = lane + it * 64;         // 512 chunks per wave
            int row = c >> 3, c8 = c & 7;
            int idx = row * 64 + 8 * (c8 ^ (row & 7));
            s8v val = *(const s8v*)&Zw[idx];
            if (which == 0)
                *(s8v*)(outq + (size_t)(gmb + row) * 1024 + gnb + c8 * 8) = val;
            else if (which == 1)
                *(s8v*)(outk + (size_t)(gmb + row) * 1024 + (gnb - 1024) + c8 * 8) = val;
            else
                *(s8v*)(outvT + (size_t)(gnb - 2048 + row) * 4096 + gmb + c8 * 8) = val;
        }
    } else {
        #pragma unroll
        for (int nb = 0; nb < 2; ++nb) {
            int gcol = n0 + 64 * wn + 32 * nb + l31;
            float bv = bias[gcol];
            #pragma unroll
            for (int mb = 0; mb < 2; ++mb)
                #pragma unroll
                for (int r = 0; r < 16; ++r) {
                    int gm = m0 + 64 * wm + 32 * mb + (r & 3) + 8 * (r >> 2) + 4 * hi;
                    outf[(size_t)gm * 1024 + gcol] = acc[mb][nb][r] + bv;
                }
        }
    }
}

// ===========================================================================
// Flash attention, bf16 MFMA. Block = 128 q rows x head x batch, 4 waves
// (32 q cols each, swapped QK^T). Double-buffered global_load_lds staging,
// ONE barrier per k-tile (loads for kt+1 issued after the barrier fly under
// compute of kt; the implicit vmcnt(0)-before-barrier drains them).
// q is pre-scaled by 0.125*log2e -> scores already in log2 units.
// ===========================================================================
__global__ __launch_bounds__(256) void attn_mfma(
    const u16* __restrict__ qp, const u16* __restrict__ kp,
    const u16* __restrict__ vTp, u16* __restrict__ zp)
{
    __shared__ u16 sm[16384];           // 2 bufs x (K 64x64 + V 64x64) = 32KB
    const int tid = threadIdx.x;
    const int lane = tid & 63, w = tid >> 6;
    const int l31 = lane & 31, hi = lane >> 5;
    const int qt = (int)gridDim.x - 1 - (int)blockIdx.x;   // heavy tiles first
    const int n = blockIdx.y, b = blockIdx.z;
    const int q0 = qt * 128;
    const int qrow = q0 + 32 * w + l31;
    const int wqmin = q0 + 32 * w, wqmax = wqmin + 31;
    const size_t mrow = (size_t)b * 2048 + qrow;
    const int srow = lane >> 3;
    const int sc8 = (lane & 7) ^ srow;
    const int rx = l31 & 7;

    // Q fragments (B-operand), hoisted: lane holds Q[q=l31][h=16c+8hi+j]
    s8v qf[4];
    #pragma unroll
    for (int c = 0; c < 4; ++c)
        qf[c] = *(const s8v*)(qp + mrow * 1024 + n * 64 + c * 16 + hi * 8);

    f16v acc[2];
    #pragma unroll
    for (int mb = 0; mb < 2; ++mb)
        #pragma unroll
        for (int r = 0; r < 16; ++r) acc[mb][r] = 0.f;
    float mrun = NINF, lrun = 0.f;
    const int nkt = 2 * qt + 2;

    auto STAGE = [&](int kt, int bufi) {
        u16* Kd = sm + bufi * 8192;
        u16* Vd = Kd + 4096;
        #pragma unroll
        for (int i = 0; i < 2; ++i) {           // 4 waves x 2 issues x 1KB per array
            const int rb = (i * 4 + w) * 8;
            const int row = rb + srow;
            gload16(kp + ((size_t)b * 2048 + kt * 64 + row) * 1024 + n * 64 + sc8 * 8,
                    Kd + rb * 64);
            gload16(vTp + ((size_t)n * 64 + row) * 4096 + b * 2048 + kt * 64 + sc8 * 8,
                    Vd + rb * 64);
        }
    };

    STAGE(0, 0);
    int cur = 0;
    for (int kt = 0; kt < nkt; ++kt) {
        __syncthreads();    // drains all waves' loads for buf[cur]; prev reads done
        if (kt + 1 < nkt) STAGE(kt + 1, cur ^ 1);   // fly under compute
        if (64 * kt <= wqmax) {
            const u16* Kd = sm + cur * 8192;
            const u16* Vd = Kd + 4096;

            // ---- QK^T (swapped): sf[t] = S[s=32t+..][q=l31], log2 units ----
            f16v sf[2];
            #pragma unroll
            for (int t = 0; t < 2; ++t) {
                #pragma unroll
                for (int r = 0; r < 16; ++r) sf[t][r] = 0.f;
                const int row = 32 * t + l31;
                #pragma unroll
                for (int c = 0; c < 4; ++c) {
                    s8v kf = *(const s8v*)&Kd[row * 64 + ((2 * c + hi) ^ rx) * 8];
                    sf[t] = MFMA32(kf, qf[c], sf[t]);
                }
            }

            // ---- causal mask: only on wave-uniform diagonal tiles ----
            if (64 * kt + 63 > wqmin) {
                #pragma unroll
                for (int t = 0; t < 2; ++t)
                    #pragma unroll
                    for (int r = 0; r < 16; ++r) {
                        const int sg = kt * 64 + 32 * t + (r & 3) + 8 * (r >> 2) + 4 * hi;
                        if (sg > qrow) sf[t][r] = NINF;
                    }
            }

            // ---- online softmax: 4-way tree max, defer-max (T13) ----
            float ma = NINF, mb2 = NINF, mc = NINF, md = NINF;
            #pragma unroll
            for (int t = 0; t < 2; ++t)
                #pragma unroll
                for (int r = 0; r < 16; r += 4) {
                    ma  = fmaxf(ma,  sf[t][r]);
                    mb2 = fmaxf(mb2, sf[t][r + 1]);
                    mc  = fmaxf(mc,  sf[t][r + 2]);
                    md  = fmaxf(md,  sf[t][r + 3]);
                }
            float mloc = fmaxf(fmaxf(ma, mb2), fmaxf(mc, md));
            mloc = fmaxf(mloc, __shfl_xor(mloc, 32, 64));

            float mbase;
            bool defer = (mloc - mrun <= 8.0f);     // P bounded by 2^8
            if (__all(defer)) {
                mbase = mrun;                        // skip rescale entirely
            } else {
                float mnew = fmaxf(mrun, mloc);
                float alpha = exp2f(mrun - mnew);
                lrun *= alpha;
                #pragma unroll
                for (int mb = 0; mb < 2; ++mb)
                    #pragma unroll
                    for (int r = 0; r < 16; ++r) acc[mb][r] *= alpha;
                mrun = mnew;
                mbase = mnew;
            }
            float sa = 0.f, sb = 0.f, sc2 = 0.f, sd = 0.f;
            #pragma unroll
            for (int t = 0; t < 2; ++t)
                #pragma unroll
                for (int r = 0; r < 16; r += 4) {
                    float p0 = exp2f(sf[t][r]     - mbase);
                    float p1 = exp2f(sf[t][r + 1] - mbase);
                    float p2 = exp2f(sf[t][r + 2] - mbase);
                    float p3 = exp2f(sf[t][r + 3] - mbase);
                    sf[t][r] = p0; sf[t][r + 1] = p1;
                    sf[t][r + 2] = p2; sf[t][r + 3] = p3;
                    sa += p0; sb += p1; sc2 += p2; sd += p3;
                }
            float ls = (sa + sb) + (sc2 + sd);
            ls += __shfl_xor(ls, 32, 64);
            lrun += ls;

            // ---- P fragization via v_cvt_pk_bf16_f32 + one shfl exchange ----
            s8v pf[4];
            #pragma unroll
            for (int c = 0; c < 4; ++c) {
                const int i0 = 2 * c, i1 = 2 * c + 1;
                const int t0 = i0 >> 2, u0 = i0 & 3;
                const int t1 = i1 >> 2, u1 = i1 & 3;
                unsigned int f00 = cvtpk(sf[t0][4 * u0 + 0], sf[t0][4 * u0 + 1]);
                unsigned int f01 = cvtpk(sf[t0][4 * u0 + 2], sf[t0][4 * u0 + 3]);
                unsigned int f10 = cvtpk(sf[t1][4 * u1 + 0], sf[t1][4 * u1 + 1]);
                unsigned int f11 = cvtpk(sf[t1][4 * u1 + 2], sf[t1][4 * u1 + 3]);
                unsigned int s0 = hi ? f00 : f10, s1 = hi ? f01 : f11;
                unsigned int r0 = __shfl_xor(s0, 32, 64);
                unsigned int r1 = __shfl_xor(s1, 32, 64);
                FragU f;
                f.u[0] = hi ? r0 : f00;  f.u[1] = hi ? r1 : f01;
                f.u[2] = hi ? f10 : r0;  f.u[3] = hi ? f11 : r1;
                pf[c] = f.v;
            }

            // ---- PV: acc[mb] += V^T x P  (D[h][q]) ----
            #pragma unroll
            for (int mb = 0; mb < 2; ++mb) {
                const int row = 32 * mb + l31;
                #pragma unroll
                for (int c = 0; c < 4; ++c) {
                    s8v vf = *(const s8v*)&Vd[row * 64 + ((2 * c + hi) ^ rx) * 8];
                    acc[mb] = MFMA32(vf, pf[c], acc[mb]);
                }
            }
        }
        cur ^= 1;
    }

    // ---- epilogue: z = acc/l -> bf16, per-wave LDS bounce, 16B stores ----
    __syncthreads();
    float linv = 1.0f / lrun;
    u16* Z = sm + w * 2048;                 // 32 rows x 64 h per wave
    #pragma unroll
    for (int mb = 0; mb < 2; ++mb)
        #pragma unroll
        for (int r = 0; r < 16; ++r) {
            int hcol = 32 * mb + (r & 3) + 8 * (r >> 2) + 4 * hi;
            int idx = l31 * 64 + (hcol ^ ((l31 & 7) << 3));
            Z[idx] = f2bf(acc[mb][r] * linv);
        }
    __syncthreads();
    #pragma unroll
    for (int it = 0; it < 4; ++it) {
        int c = lane + it * 64;             // 256 chunks per wave
        int row = c >> 3, c8 = c & 7;
        int idx = row * 64 + 8 * (c8 ^ (row & 7));
        *(s8v*)(zp + ((size_t)b * 2048 + q0 + 32 * w + row) * 1024 + n * 64 + c8 * 8) =
            *(const s8v*)&Z[idx];
    }
}

// ===========================================================================
extern "C" void kernel_launch(void* const* d_in, const int* in_sizes, int n_in,
                              void* d_out, int out_size, void* d_ws, size_t ws_size,
                              hipStream_t stream) {
    const float* x  = (const float*)d_in[0];
    const float* Wq = (const float*)d_in[1];
    const float* Wk = (const float*)d_in[2];
    const float* Wv = (const float*)d_in[3];
    const float* Wo = (const float*)d_in[4];
    const float* bq = (const float*)d_in[5];
    const float* bk = (const float*)d_in[6];
    const float* bv = (const float*)d_in[7];
    const float* bO = (const float*)d_in[8];
    float* out = (float*)d_out;

    char* p = (char*)d_ws;
    size_t o = 0;
    auto alloc = [&](size_t bytes) { char* r = p + o; o += bytes; return r; };
    const size_t MB8 = (size_t)M_ * D_ * 2;            // 8 MB bf16 buffer
    u16* xb   = (u16*)alloc(MB8);
    u16* Wc   = (u16*)alloc((size_t)3072 * 1024 * 2);
    u16* WoT  = (u16*)alloc((size_t)1024 * 1024 * 2);
    float* bc = (float*)alloc(65536);
    u16* qb   = (u16*)alloc(MB8);
    u16* kb   = (u16*)alloc(MB8);
    u16* vTb  = (u16*)alloc(MB8);
    if (ws_size < o) return;
    u16* zb = xb;   // x dead after qkv gemm; reuse for z

    cvt_x<<<2048, 256, 0, stream>>>(x, xb);
    transW_kernel<<<dim3(16, 16, 3), 256, 0, stream>>>(Wq, Wk, Wv, Wc);
    transWo_kernel<<<dim3(16, 16), 256, 0, stream>>>(Wo, WoT);
    bcat_kernel<<<12, 256, 0, stream>>>(bq, bk, bv, bc);
    gemm_bf16<0><<<dim3(32, 24), 256, 0, stream>>>(
        xb, Wc, bc, qb, kb, vTb, nullptr);
    attn_mfma<<<dim3(16, 16, 2), 256, 0, stream>>>(qb, kb, vTb, zb);
    gemm_bf16<1><<<dim3(32, 8), 256, 0, stream>>>(
        zb, WoT, bO, nullptr, nullptr, nullptr, out);
}